// Round 12
// baseline (108.808 us; speedup 1.0000x reference)
//
#include <hip/hip_runtime.h>
#include <hip/hip_bf16.h>

#define SEQ 2048
#define EMB 1024
#define DH  128
#define QSCALE 0.08838834764831845f  // 1/sqrt(128)

typedef __attribute__((ext_vector_type(4))) float f32x4;
typedef __attribute__((ext_vector_type(4))) unsigned u32x4;
typedef __attribute__((ext_vector_type(8))) short bf16x8;
typedef __attribute__((ext_vector_type(4))) short bf16x4;

__device__ __forceinline__ short f2bf(float f) {
  unsigned u = __builtin_bit_cast(unsigned, f);
  u += 0x7fffu + ((u >> 16) & 1u);   // RNE
  return (short)(u >> 16);
}

__device__ __forceinline__ float bf2f(short s) {
  unsigned u = ((unsigned)(unsigned short)s) << 16;
  return __builtin_bit_cast(float, u);
}

// HW packed f32->bf16 (RNE on gfx950): dst = {lo16: cvt(a), hi16: cvt(b)}
__device__ __forceinline__ unsigned cvt_pk2(float a, float b) {
  unsigned r;
  asm("v_cvt_pk_bf16_f32 %0, %1, %2" : "=v"(r) : "v"(a), "v"(b));
  return r;
}

__device__ __forceinline__ f32x4 mfma16(bf16x8 a, bf16x8 b, f32x4 c) {
  return __builtin_amdgcn_mfma_f32_16x16x32_bf16(a, b, c, 0, 0, 0);
}

// async global->LDS, 16B per lane; lds_base must be wave-uniform (HW adds lane*16)
__device__ __forceinline__ void gl_lds16(void* lds_base, const void* gsrc) {
  __builtin_amdgcn_global_load_lds(
      (const __attribute__((address_space(1))) void*)gsrc,
      (__attribute__((address_space(3))) void*)lds_base, 16, 0, 0);
}

// ---------------- weight prep ----------------
// W[E][128] f32 -> wt[p][kk][nb][lane][8] bf16 (exact B-fragment order for
// mfma_f32_16x16x32_bf16: lane l holds B[k = kk*32 + (l>>4)*8 + j][n = nb*16 + (l&15)]).
__global__ void prep_weights(const float* __restrict__ Wq, const float* __restrict__ Wk,
                             const float* __restrict__ Wv, short* __restrict__ wt) {
  int gid = blockIdx.x * 256 + threadIdx.x;
  int lane = gid & 63, c = lane & 15, g = (lane >> 4) & 3;
  int nb = (gid >> 6) & 7;
  int kk = (gid >> 9) & 31;
  int p = gid >> 14;
  const float* W = (p == 0) ? Wq : ((p == 1) ? Wk : Wv);
  bf16x8 v;
#pragma unroll
  for (int j = 0; j < 8; ++j)
    v[j] = f2bf(W[(kk * 32 + g * 8 + j) * DH + nb * 16 + c]);
  *(bf16x8*)(&wt[(size_t)gid * 8]) = v;
}

// ---------------- projection GEMM: persistent-W, 2 blocks/CU cross-overlap ----------
// R11 post-mortem: per-CU delivery tracks CONCURRENT STAGING STREAMS, not pipeline
// depth (R0 3blk/CU=19.6 GB/s/CU, R8 2blk/CU=36, R11 1blk/CU=9). R11's double-buffer
// exposed ~5us stage latency every tile because nothing else runs on the CU.
// v12: single 64KB A-buffer -> LDS 65536 -> 2 RESIDENT BLOCKS/CU; within a block,
// stage->vmcnt(0)->compute serialize, and the co-resident block fills the stall
// (stage:compute ~ 5:1). Persistent-W asm loads, cvt_pk fragment conversion, dense
// swizzled staging, stores: byte-identical to R11 (passed, FETCH exact, 0 conflicts).
__global__ __launch_bounds__(512, 1) void proj_gemm(
    const float* __restrict__ Xq, const float* __restrict__ Xk, const float* __restrict__ Xv,
    const short* __restrict__ wt,
    const float* __restrict__ bq, const float* __restrict__ bk, const float* __restrict__ bv,
    short* __restrict__ qp, short* __restrict__ kp, short* __restrict__ vt) {
  __shared__ char a_lds[65536];   // single buffer: 16 rows x 4KB, swizzled within row

  const int tid = threadIdx.x;
  const int w = tid >> 6, lane = tid & 63;
  const int g = lane >> 4, c = lane & 15;
  const int p = blockIdx.x >> 8;              // wave-uniform projection id
  const int lt0 = (blockIdx.x & 255) << 2;    // first of 4 consecutive 16-token tiles
  const float* X    = (p == 0) ? Xq : ((p == 1) ? Xk : Xv);
  const float* bias = (p == 0) ? bq : ((p == 1) ? bk : bv);
  const char* Xbase = (const char*)X + (size_t)lt0 * 65536;
  short* outp = (p == 0) ? qp : kp;
  const float sc = (p == 0) ? QSCALE : 1.0f;

  // ---- persistent W: wave w holds cols [16w,16w+16) x full K via asm loads ----
  f32x4 wr[32];
  float bval;
  {
    const char* Wp = (const char*)wt + (size_t)p * 262144 + (size_t)w * 1024 + (lane << 4);
#pragma unroll
    for (int kk = 0; kk < 32; ++kk) {
      asm volatile("global_load_dwordx4 %0, %1, off"
                   : "=v"(wr[kk]) : "v"(Wp + (size_t)kk * 8192));
    }
    bval = bias[(w << 4) + c];
  }
  __builtin_amdgcn_sched_barrier(0);   // pin: W/bias loads issued before first stage

  // stage tile i's 16 rows x 4KB; this wave's 8 of 64 contiguous-KB chunks.
  // Source pre-XOR-swizzled within each row's 4KB (bits 4-7 by row&15); linear LDS dest.
  auto stageA = [&](int i) {
    const char* Xt = Xbase + (size_t)i * 65536;
#pragma unroll
    for (int j = 0; j < 8; ++j) {
      int id = (w << 3) | j;          // 0..63
      int row = id >> 2, q = id & 3;
      gl_lds16(a_lds + (row << 12) + (q << 10),
               Xt + (row << 12) + (q << 10) + ((lane << 4) ^ ((row & 15) << 4)));
    }
  };

#pragma unroll 1
  for (int i = 0; i < 4; ++i) {
    if (i) __builtin_amdgcn_s_barrier();   // WAR: all waves done reading buf (iter i-1)
    stageA(i);
    __builtin_amdgcn_sched_barrier(0);
    asm volatile("s_waitcnt vmcnt(0)" ::: "memory");   // stage(i) (+W at i=0, stores) done
    __builtin_amdgcn_sched_barrier(0);
    __builtin_amdgcn_s_barrier();          // RAW: all waves' stage(i) landed

    // ---- compute tile i: wave w -> C[16 rows][cols 16w..16w+16) ----
    f32x4 acc = (f32x4){0.f, 0.f, 0.f, 0.f};
    const char* ab = a_lds + ((size_t)c << 12);   // row c of the tile
#pragma unroll
    for (int kk = 0; kk < 32; ++kk) {
      int ad = ((kk << 7) + (g << 5)) ^ ((c & 15) << 4);
      f32x4 lo = *(const f32x4*)(ab + ad);
      f32x4 hi = *(const f32x4*)(ab + (ad ^ 16));
      bf16x8 a = __builtin_bit_cast(bf16x8,
          (u32x4){cvt_pk2(lo[0], lo[1]), cvt_pk2(lo[2], lo[3]),
                  cvt_pk2(hi[0], hi[1]), cvt_pk2(hi[2], hi[3])});
      acc = mfma16(a, __builtin_bit_cast(bf16x8, wr[kk]), acc);
    }
    __builtin_amdgcn_sched_barrier(0);

    // ---- store tile i: C row = g*4+r, col = w*16+c ----
    const int row0 = (lt0 + i) << 4;
    if (p < 2) {                       // q (scaled) / k, row-major [token][128] bf16
#pragma unroll
      for (int r = 0; r < 4; ++r) {
        int token = row0 + g * 4 + r;
        outp[token * 128 + (w << 4) + c] = f2bf((acc[r] + bval) * sc);
      }
    } else {                           // v transposed: vT[b][d][s] bf16
      int tok0 = row0 + g * 4;
      int b_ = tok0 >> 11, s_ = tok0 & 2047;
      int col = (w << 4) + c;
      bf16x4 v4;
#pragma unroll
      for (int r = 0; r < 4; ++r) v4[r] = f2bf(acc[r] + bval);
      *(bf16x4*)(&vt[((size_t)(b_ * 128 + col)) * 2048 + s_]) = v4;
    }
    __builtin_amdgcn_sched_barrier(0); // pin stores before next iter's barrier/stage
  }
}

// ---------------- avgV from projected V (degenerate-row fixup) ----------------
// avgv[b][d] = mean over padded s of vt[b][d][s]  (vt already includes bias)
__global__ __launch_bounds__(256) void avgv2_kernel(
    const short* __restrict__ vt, const int* __restrict__ pad,
    const float* __restrict__ bvv, float* __restrict__ avgv) {
  int b = blockIdx.x >> 3, dg = blockIdx.x & 7;
  int t = threadIdx.x, doff = t >> 4, sl = t & 15;
  int d = dg * 16 + doff;
  const short* vrow = vt + ((size_t)(b * 128 + d)) * 2048 + sl * 128;
  const int* prow = pad + (b << 11) + sl * 128;
  float sum = 0.f;
  int cnt = 0;
  for (int i = 0; i < 16; ++i) {
    bf16x8 v8 = *(const bf16x8*)(vrow + i * 8);
#pragma unroll
    for (int j = 0; j < 8; ++j) {
      int pd = prow[i * 8 + j];
      cnt += (pd != 0);
      if (pd) sum += bf2f(v8[j]);
    }
  }
#pragma unroll
  for (int xm = 1; xm < 16; xm <<= 1) {
    sum += __shfl_xor(sum, xm, 64);
    cnt += __shfl_xor(cnt, xm, 64);
  }
  if (sl == 0) avgv[(b << 7) + d] = (cnt > 0) ? (sum / (float)cnt) : 0.f;
  (void)bvv;
}

// ---------------- flash attention (causal, split-KV x2, double-buffered) ----------------
__device__ __forceinline__ void stage_kv(short* kb, short* vb,
                                         const char* kb_base, const char* vb_base,
                                         int kt, int w, int lane) {
#pragma unroll
  for (int ch = w; ch < 16; ch += 4) {   // K tile [key][d], swizzled 256B rows
    int phys = ch * 1024 + lane * 16;
    int lg = phys ^ (((phys >> 8) & 7) << 4);
    gl_lds16((char*)kb + ch * 1024,
             kb_base + (size_t)(kt * 64 + (lg >> 8)) * 256 + (lg & 255));
  }
#pragma unroll
  for (int ch = w; ch < 16; ch += 4) {   // V^T tile [d][key], swizzled 128B rows
    int phys = ch * 1024 + lane * 16;
    int lg = phys ^ (((phys >> 7) & 7) << 4);
    gl_lds16((char*)vb + ch * 1024,
             vb_base + (size_t)(lg >> 7) * 4096 + kt * 128 + (lg & 127));
  }
}

template <bool CAUSAL>
__device__ __forceinline__ void attn_tile(
    const short* __restrict__ k_lds, const short* __restrict__ v_lds, short* __restrict__ p_w,
    const bf16x8 (&qf)[4], f32x4 (&acc_o)[8], float (&m_r)[4], float (&l_r)[4],
    const int* __restrict__ padp, int kt, int qrow_g, int g, int c) {
  f32x4 sc[4];
#pragma unroll
  for (int nb = 0; nb < 4; ++nb) sc[nb] = (f32x4){0.f, 0.f, 0.f, 0.f};
#pragma unroll
  for (int ks = 0; ks < 4; ++ks) {
    bf16x8 kf[4];
#pragma unroll
    for (int nb = 0; nb < 4; ++nb) {
      int n = (nb << 4) + c;
      int off = (n << 8) + (ks << 6) + (g << 4);
      kf[nb] = *(const bf16x8*)((const char*)k_lds + (off ^ ((n & 7) << 4)));
    }
#pragma unroll
    for (int nb = 0; nb < 4; ++nb) sc[nb] = mfma16(qf[ks], kf[nb], sc[nb]);
  }

  int padv[4];
#pragma unroll
  for (int nb = 0; nb < 4; ++nb) padv[nb] = padp[kt + (nb << 4) + c];
  float sv[4][4];
#pragma unroll
  for (int nb = 0; nb < 4; ++nb) {
    bool pd = padv[nb] != 0;
    int key = kt + (nb << 4) + c;
#pragma unroll
    for (int r = 0; r < 4; ++r) {
      float s = sc[nb][r];
      if (CAUSAL && key > qrow_g + r) s = -1e30f;
      if (pd) s = -1e30f;
      sv[nb][r] = s;
    }
  }
  float tmax[4];
#pragma unroll
  for (int r = 0; r < 4; ++r)
    tmax[r] = fmaxf(fmaxf(sv[0][r], sv[1][r]), fmaxf(sv[2][r], sv[3][r]));
#pragma unroll
  for (int xm = 1; xm < 16; xm <<= 1)
#pragma unroll
    for (int r = 0; r < 4; ++r) tmax[r] = fmaxf(tmax[r], __shfl_xor(tmax[r], xm, 64));
  float al[4];
#pragma unroll
  for (int r = 0; r < 4; ++r) {
    float mn = fmaxf(m_r[r], tmax[r]);
    al[r] = __expf(m_r[r] - mn);
    m_r[r] = mn;
  }
  float ls[4] = {0.f, 0.f, 0.f, 0.f};
#pragma unroll
  for (int nb = 0; nb < 4; ++nb)
#pragma unroll
    for (int r = 0; r < 4; ++r) {
      float pp = __expf(sv[nb][r] - m_r[r]);
      sv[nb][r] = pp;
      ls[r] += pp;
    }
#pragma unroll
  for (int xm = 1; xm < 16; xm <<= 1)
#pragma unroll
    for (int r = 0; r < 4; ++r) ls[r] += __shfl_xor(ls[r], xm, 64);
#pragma unroll
  for (int r = 0; r < 4; ++r) l_r[r] = l_r[r] * al[r] + ls[r];
#pragma unroll
  for (int nb = 0; nb < 8; ++nb)
#pragma unroll
    for (int r = 0; r < 4; ++r) acc_o[nb][r] *= al[r];

#pragma unroll
  for (int nb = 0; nb < 4; ++nb)
#pragma unroll
    for (int r = 0; r < 4; ++r)
      p_w[(g * 4 + r) * 72 + (nb << 4) + c] = f2bf(sv[nb][r]);

#pragma unroll
  for (int ks = 0; ks < 2; ++ks) {
    bf16x8 pa = *(const bf16x8*)((const char*)p_w + c * 144 + ks * 64 + g * 16);
#pragma unroll
    for (int nb = 0; nb < 8; ++nb) {
      int n = (nb << 4) + c;
      int off = (n << 7) + (ks << 6) + (g << 4);
      bf16x8 vf = *(const bf16x8*)((const char*)v_lds + (off ^ ((n & 7) << 4)));
      acc_o[nb] = mfma16(pa, vf, acc_o[nb]);
    }
  }
}

// work map: j<256 -> (b=j>>5, qi=j&31, half0: tiles [0,T/2));
//           j>=256 -> (b, qi=31-(u&31), half1: tiles [T/2,T)). Pairs (j, j+256) balance.
__global__ __launch_bounds__(256) void flash_attn(
    const short* __restrict__ qp, const short* __restrict__ kp, const short* __restrict__ vt,
    const int* __restrict__ pad, float* __restrict__ partO, float* __restrict__ partML) {
  __shared__ short k_lds[2][64 * 128];
  __shared__ short v_lds[2][128 * 64];
  __shared__ short p_lds[4][16 * 72];
  const int tid = threadIdx.x, w = tid >> 6, lane = tid & 63;
  const int g = lane >> 4, c = lane & 15;
  const int j = blockIdx.x;
  int b, qi, half;
  if (j < 256) { b = j >> 5; qi = j & 31; half = 0; }
  else { int u = j - 256; b = u >> 5; qi = 31 - (u & 31); half = 1; }
  const int T = qi + 1;
  const int t0 = half ? (T >> 1) : 0;
  const int t1 = half ? T : (T >> 1);
  const int q0 = qi << 6;

  bf16x8 qf[4];
  {
    int token = (b << 11) + q0 + (w << 4) + c;
    const char* qrow = (const char*)qp + (size_t)token * 256;
#pragma unroll
    for (int s = 0; s < 4; ++s) qf[s] = *(const bf16x8*)(qrow + s * 64 + g * 16);
  }
  f32x4 acc_o[8];
#pragma unroll
  for (int i = 0; i < 8; ++i) acc_o[i] = (f32x4){0.f, 0.f, 0.f, 0.f};
  float m_r[4] = {-1e30f, -1e30f, -1e30f, -1e30f};
  float l_r[4] = {0.f, 0.f, 0.f, 0.f};

  const char* kb_base = (const char*)kp + (size_t)(b << 11) * 256;
  const char* vb_base = (const char*)vt + (size_t)b * 524288;
  const int* padp = pad + (b << 11);
  const int qrow_g = q0 + (w << 4) + (g << 2);

  if (t1 > t0) {
    stage_kv(k_lds[0], v_lds[0], kb_base, vb_base, t0, w, lane);
    __syncthreads();
    int cur = 0;
    for (int t = t0; t < t1; ++t) {
      if (t + 1 < t1)
        stage_kv(k_lds[cur ^ 1], v_lds[cur ^ 1], kb_base, vb_base, t + 1, w, lane);
      if (half && t == T - 1)
        attn_tile<true>(k_lds[cur], v_lds[cur], p_lds[w], qf, acc_o, m_r, l_r,
                        padp, t << 6, qrow_g, g, c);
      else
        attn_tile<false>(k_lds[cur], v_lds[cur], p_lds[w], qf, acc_o, m_r, l_r,
                         padp, t << 6, qrow_g, g, c);
      __syncthreads();
      cur ^= 1;
    }
  }

  float* pO = partO + (size_t)j * (64 * 128);
  float* pML = partML + (size_t)j * 128;
#pragma unroll
  for (int nb = 0; nb < 8; ++nb)
#pragma unroll
    for (int r = 0; r < 4; ++r)
      pO[(w * 16 + g * 4 + r) * 128 + (nb << 4) + c] = acc_o[nb][r];
  if (c == 0)
#pragma unroll
    for (int r = 0; r < 4; ++r) {
      pML[(w * 16 + g * 4 + r) * 2] = m_r[r];
      pML[(w * 16 + g * 4 + r) * 2 + 1] = l_r[r];
    }
}

// ---------------- combine: merge 2 partials, degenerate fixup ----------------
__global__ __launch_bounds__(256) void combine_kernel(
    const float* __restrict__ partO, const float* __restrict__ partML,
    const float* __restrict__ avgv, float* __restrict__ out) {
  int gid = blockIdx.x * 256 + threadIdx.x;   // 524288 float4s
  int row = gid >> 5;
  int d4 = gid & 31;
  int b = row >> 11, s = row & 2047;
  int qt = s >> 6, lr = s & 63;
  int wid1 = (b << 5) + qt;
  int wid2 = 256 + (b << 5) + (31 - qt);
  float m1 = partML[wid1 * 128 + lr * 2], l1 = partML[wid1 * 128 + lr * 2 + 1];
  float m2 = partML[wid2 * 128 + lr * 2], l2 = partML[wid2 * 128 + lr * 2 + 1];
  float m = fmaxf(m1, m2);
  f32x4 o;
  if (m < -1e8f) {
    o = *(const f32x4*)(avgv + (b << 7) + (d4 << 2));
  } else {
    float f1 = __expf(m1 - m), f2 = __expf(m2 - m);
    float inv = 1.0f / (l1 * f1 + l2 * f2);
    f32x4 o1 = *(const f32x4*)(partO + ((size_t)wid1 * 64 + lr) * 128 + (d4 << 2));
    f32x4 o2 = *(const f32x4*)(partO + ((size_t)wid2 * 64 + lr) * 128 + (d4 << 2));
#pragma unroll
    for (int k = 0; k < 4; ++k) o[k] = (o1[k] * f1 + o2[k] * f2) * inv;
  }
  *(f32x4*)(out + (size_t)row * 128 + (d4 << 2)) = o;
}

extern "C" void kernel_launch(void* const* d_in, const int* in_sizes, int n_in,
                              void* d_out, int out_size, void* d_ws, size_t ws_size,
                              hipStream_t stream) {
  const int*   pad   = (const int*)d_in[0];
  const float* query = (const float*)d_in[1];
  const float* key   = (const float*)d_in[2];
  const float* value = (const float*)d_in[3];
  const float* Wq    = (const float*)d_in[4];
  const float* bq    = (const float*)d_in[5];
  const float* Wk    = (const float*)d_in[6];
  const float* bk    = (const float*)d_in[7];
  const float* Wv    = (const float*)d_in[8];
  const float* bv    = (const float*)d_in[9];
  char* ws = (char*)d_ws;
  short* wt    = (short*)ws;                      // 768KB (fragment-ordered)
  short* qp    = (short*)(ws + 786432);           // 4MB
  short* kp    = (short*)(ws + 4980736);          // 4MB
  short* vt    = (short*)(ws + 9175040);          // 4MB  vT[8][128][2048]
  float* partO = (float*)(ws + 13369344);         // 512*64*128*4 = 16MB
  float* partML= (float*)(ws + 30146560);         // 512*64*2*4 = 256KB
  float* avgv  = (float*)(ws + 30408704);         // 4KB
  float* out   = (float*)d_out;

  prep_weights<<<dim3(192), dim3(256), 0, stream>>>(Wq, Wk, Wv, wt);
  proj_gemm<<<dim3(768), dim3(512), 0, stream>>>(query, key, value, wt, bq, bk, bv, qp, kp, vt);
  avgv2_kernel<<<dim3(64), dim3(256), 0, stream>>>(vt, pad, bv, avgv);
  flash_attn<<<dim3(512), dim3(256), 0, stream>>>(qp, kp, vt, pad, partO, partML);
  combine_kernel<<<dim3(2048), dim3(256), 0, stream>>>(partO, partML, avgv, out);
}

// Round 13
// 96.781 us; speedup vs baseline: 1.1243x; 1.1243x over previous
//
#include <hip/hip_runtime.h>
#include <hip/hip_bf16.h>

#define SEQ 2048
#define EMB 1024
#define DH  128
#define QSCALE 0.08838834764831845f  // 1/sqrt(128)

typedef __attribute__((ext_vector_type(4))) float f32x4;
typedef __attribute__((ext_vector_type(8))) short bf16x8;
typedef __attribute__((ext_vector_type(4))) short bf16x4;

__device__ __forceinline__ short f2bf(float f) {
  unsigned u = __builtin_bit_cast(unsigned, f);
  u += 0x7fffu + ((u >> 16) & 1u);   // RNE
  return (short)(u >> 16);
}

__device__ __forceinline__ float bf2f(short s) {
  unsigned u = ((unsigned)(unsigned short)s) << 16;
  return __builtin_bit_cast(float, u);
}

__device__ __forceinline__ f32x4 mfma16(bf16x8 a, bf16x8 b, f32x4 c) {
  return __builtin_amdgcn_mfma_f32_16x16x32_bf16(a, b, c, 0, 0, 0);
}

// async global->LDS, 16B per lane; lds_base must be wave-uniform (HW adds lane*16)
__device__ __forceinline__ void gl_lds16(void* lds_base, const void* gsrc) {
  __builtin_amdgcn_global_load_lds(
      (const __attribute__((address_space(1))) void*)gsrc,
      (__attribute__((address_space(3))) void*)lds_base, 16, 0, 0);
}

// ---------------- weight prep ----------------
// W[E][128] f32 -> wt[p][kk][nb][lane][8] bf16 (exact B-fragment order for
// mfma_f32_16x16x32_bf16: lane l holds B[k = kk*32 + (l>>4)*8 + j][n = nb*16 + (l&15)]).
__global__ void prep_weights(const float* __restrict__ Wq, const float* __restrict__ Wk,
                             const float* __restrict__ Wv, short* __restrict__ wt) {
  int gid = blockIdx.x * 256 + threadIdx.x;
  int lane = gid & 63, c = lane & 15, g = (lane >> 4) & 3;
  int nb = (gid >> 6) & 7;
  int kk = (gid >> 9) & 31;
  int p = gid >> 14;
  const float* W = (p == 0) ? Wq : ((p == 1) ? Wk : Wv);
  bf16x8 v;
#pragma unroll
  for (int j = 0; j < 8; ++j)
    v[j] = f2bf(W[(kk * 32 + g * 8 + j) * DH + nb * 16 + c]);
  *(bf16x8*)(&wt[(size_t)gid * 8]) = v;
}

// ---------------- projection GEMM: 4-wave T3/T4 pipeline (best measured, R5) --------
// Final config. 13 structural variants (reg-pipelines, granularity, K-phase rotation,
// flat-vs-gl_lds transport, dense whole-tile staging, persistent-W registers,
// cross-block overlap) all pin the A-stream at 2.3-2.5 TB/s delivered -> proj floor
// ~80us. This config (with R0's baseline) sits ON that floor: 256-thread blocks
// (4 waves), 768 blocks = 3 blocks/CU = 12 waves/CU, counted vmcnt(4) + RAW s_barrier
// (no vmcnt(0) drain), 3-buffer LDS ring, stage-1-ahead, per-block K-rotation.
// WAR safety: buf[t%3] next written for tile t+3 at iter t+2, which all waves reach
// only after barrier(t+1), which follows every wave's compute(t) reads.
__global__ __launch_bounds__(256, 3) void proj_gemm(
    const float* __restrict__ Xq, const float* __restrict__ Xk, const float* __restrict__ Xv,
    const short* __restrict__ wt,
    const float* __restrict__ bq, const float* __restrict__ bk, const float* __restrict__ bv,
    short* __restrict__ qp, short* __restrict__ kp, short* __restrict__ vt) {
  __shared__ char abuf[3][8192];   // 64 rows x 128B per buffer
  __shared__ char wbuf[3][8192];   // 8 fragment chunks x 1KB per buffer

  const int tid = threadIdx.x;
  const int w = tid >> 6, lane = tid & 63;
  const int g = lane >> 4, c = lane & 15;
  const int bid = blockIdx.x;
  const int p = bid >> 8, mb = bid & 255;
  const int row0 = mb << 6;                         // 64-row tile
  const int k0 = (bid * 5) & 31;                    // per-block K phase (free de-phasing)
  const float* X    = (p == 0) ? Xq : ((p == 1) ? Xk : Xv);
  const float* bias = (p == 0) ? bq : ((p == 1) ? bk : bv);
  const char* Xb  = (const char*)X;
  const char* Wtb = (const char*)wt + (size_t)p * 262144;

  f32x4 acc[8];
#pragma unroll
  for (int nb = 0; nb < 8; ++nb) acc[nb] = (f32x4){0.f, 0.f, 0.f, 0.f};

  // stage: this wave's 4 x 1KB share (A chunks {w,w+4} of 8, W chunks {w,w+4} of 8).
  // A source pre-XOR-swizzled (linear LDS dest, swizzle applied again on read).
  auto stage = [&](int buf, int kk) {
#pragma unroll
    for (int i = 0; i < 2; ++i) {
      int ch = w + i * 4;
      int phys = ch * 1024 + lane * 16;
      int lg = phys ^ (((phys >> 7) & 7) << 4);
      gl_lds16(abuf[buf] + ch * 1024,
               Xb + (size_t)(row0 + (lg >> 7)) * 4096 + kk * 128 + (lg & 127));
    }
#pragma unroll
    for (int i = 0; i < 2; ++i) {
      int ch = w + i * 4;
      gl_lds16(wbuf[buf] + ch * 1024,
               Wtb + (size_t)kk * 8192 + ch * 1024 + lane * 16);
    }
  };

  // compute: wave w owns block-rows w*16..w*16+15 -> 1 A fragment, 8 MFMAs.
  auto compute = [&](int buf) {
    const char* ab = abuf[buf];
    const char* wb = wbuf[buf];
    bf16x8 wfr[8];
#pragma unroll
    for (int nb = 0; nb < 8; ++nb)
      wfr[nb] = *(const bf16x8*)(wb + nb * 1024 + lane * 16);
    int r = (w << 4) + c;
    int ad = (r << 7) + ((g << 5) ^ ((r & 7) << 4));
    f32x4 lo = *(const f32x4*)(ab + ad);
    f32x4 hi = *(const f32x4*)(ab + (ad ^ 16));
    bf16x8 a;
#pragma unroll
    for (int j = 0; j < 4; ++j) { a[j] = f2bf(lo[j]); a[4 + j] = f2bf(hi[j]); }
#pragma unroll
    for (int nb = 0; nb < 8; ++nb) acc[nb] = mfma16(a, wfr[nb], acc[nb]);
  };

  stage(0, k0);
  int bufc = 0;
#pragma unroll 1
  for (int t = 0; t < 32; ++t) {
    int nbuf = (bufc == 2) ? 0 : bufc + 1;
    if (t + 1 < 32) {
      stage(nbuf, (k0 + t + 1) & 31);
      asm volatile("s_waitcnt vmcnt(4)" ::: "memory");  // retire step t's 4; keep t+1's in flight
    } else {
      asm volatile("s_waitcnt vmcnt(0)" ::: "memory");
    }
    __builtin_amdgcn_s_barrier();                       // raw barrier: no vmcnt(0) drain
    __builtin_amdgcn_sched_barrier(0);
    compute(bufc);
    bufc = nbuf;
  }

  // epilogue: C/D layout col = c, row = g*4 + reg (within this wave's 16-row tile)
  float bvals[8];
#pragma unroll
  for (int nb = 0; nb < 8; ++nb) bvals[nb] = bias[nb * 16 + c];

  if (p < 2) {   // q (scaled) / k, row-major [token][128] bf16
    short* outp = (p == 0) ? qp : kp;
    float sc = (p == 0) ? QSCALE : 1.0f;
#pragma unroll
    for (int r = 0; r < 4; ++r) {
      int token = row0 + (w << 4) + g * 4 + r;
#pragma unroll
      for (int nb = 0; nb < 8; ++nb)
        outp[token * 128 + nb * 16 + c] = f2bf((acc[nb][r] + bvals[nb]) * sc);
    }
  } else {       // v transposed: vT[b][d][s] bf16
    int tok0 = row0 + (w << 4) + g * 4;
    int b_ = tok0 >> 11, s_ = tok0 & 2047;
#pragma unroll
    for (int nb = 0; nb < 8; ++nb) {
      int col = nb * 16 + c;
      bf16x4 v4;
#pragma unroll
      for (int r = 0; r < 4; ++r) v4[r] = f2bf(acc[nb][r] + bvals[nb]);
      *(bf16x4*)(&vt[((size_t)(b_ * 128 + col)) * 2048 + s_]) = v4;
    }
  }
}

// ---------------- avgV from projected V (degenerate-row fixup) ----------------
// avgv[b][d] = mean over padded s of vt[b][d][s]  (vt already includes bias)
__global__ __launch_bounds__(256) void avgv2_kernel(
    const short* __restrict__ vt, const int* __restrict__ pad,
    const float* __restrict__ bvv, float* __restrict__ avgv) {
  int b = blockIdx.x >> 3, dg = blockIdx.x & 7;
  int t = threadIdx.x, doff = t >> 4, sl = t & 15;
  int d = dg * 16 + doff;
  const short* vrow = vt + ((size_t)(b * 128 + d)) * 2048 + sl * 128;
  const int* prow = pad + (b << 11) + sl * 128;
  float sum = 0.f;
  int cnt = 0;
  for (int i = 0; i < 16; ++i) {
    bf16x8 v8 = *(const bf16x8*)(vrow + i * 8);
#pragma unroll
    for (int j = 0; j < 8; ++j) {
      int pd = prow[i * 8 + j];
      cnt += (pd != 0);
      if (pd) sum += bf2f(v8[j]);
    }
  }
#pragma unroll
  for (int xm = 1; xm < 16; xm <<= 1) {
    sum += __shfl_xor(sum, xm, 64);
    cnt += __shfl_xor(cnt, xm, 64);
  }
  if (sl == 0) avgv[(b << 7) + d] = (cnt > 0) ? (sum / (float)cnt) : 0.f;
  (void)bvv;
}

// ---------------- flash attention (causal, split-KV x2, double-buffered) ----------------
__device__ __forceinline__ void stage_kv(short* kb, short* vb,
                                         const char* kb_base, const char* vb_base,
                                         int kt, int w, int lane) {
#pragma unroll
  for (int ch = w; ch < 16; ch += 4) {   // K tile [key][d], swizzled 256B rows
    int phys = ch * 1024 + lane * 16;
    int lg = phys ^ (((phys >> 8) & 7) << 4);
    gl_lds16((char*)kb + ch * 1024,
             kb_base + (size_t)(kt * 64 + (lg >> 8)) * 256 + (lg & 255));
  }
#pragma unroll
  for (int ch = w; ch < 16; ch += 4) {   // V^T tile [d][key], swizzled 128B rows
    int phys = ch * 1024 + lane * 16;
    int lg = phys ^ (((phys >> 7) & 7) << 4);
    gl_lds16((char*)vb + ch * 1024,
             vb_base + (size_t)(lg >> 7) * 4096 + kt * 128 + (lg & 127));
  }
}

template <bool CAUSAL>
__device__ __forceinline__ void attn_tile(
    const short* __restrict__ k_lds, const short* __restrict__ v_lds, short* __restrict__ p_w,
    const bf16x8 (&qf)[4], f32x4 (&acc_o)[8], float (&m_r)[4], float (&l_r)[4],
    const int* __restrict__ padp, int kt, int qrow_g, int g, int c) {
  f32x4 sc[4];
#pragma unroll
  for (int nb = 0; nb < 4; ++nb) sc[nb] = (f32x4){0.f, 0.f, 0.f, 0.f};
#pragma unroll
  for (int ks = 0; ks < 4; ++ks) {
    bf16x8 kf[4];
#pragma unroll
    for (int nb = 0; nb < 4; ++nb) {
      int n = (nb << 4) + c;
      int off = (n << 8) + (ks << 6) + (g << 4);
      kf[nb] = *(const bf16x8*)((const char*)k_lds + (off ^ ((n & 7) << 4)));
    }
#pragma unroll
    for (int nb = 0; nb < 4; ++nb) sc[nb] = mfma16(qf[ks], kf[nb], sc[nb]);
  }

  int padv[4];
#pragma unroll
  for (int nb = 0; nb < 4; ++nb) padv[nb] = padp[kt + (nb << 4) + c];
  float sv[4][4];
#pragma unroll
  for (int nb = 0; nb < 4; ++nb) {
    bool pd = padv[nb] != 0;
    int key = kt + (nb << 4) + c;
#pragma unroll
    for (int r = 0; r < 4; ++r) {
      float s = sc[nb][r];
      if (CAUSAL && key > qrow_g + r) s = -1e30f;
      if (pd) s = -1e30f;
      sv[nb][r] = s;
    }
  }
  float tmax[4];
#pragma unroll
  for (int r = 0; r < 4; ++r)
    tmax[r] = fmaxf(fmaxf(sv[0][r], sv[1][r]), fmaxf(sv[2][r], sv[3][r]));
#pragma unroll
  for (int xm = 1; xm < 16; xm <<= 1)
#pragma unroll
    for (int r = 0; r < 4; ++r) tmax[r] = fmaxf(tmax[r], __shfl_xor(tmax[r], xm, 64));
  float al[4];
#pragma unroll
  for (int r = 0; r < 4; ++r) {
    float mn = fmaxf(m_r[r], tmax[r]);
    al[r] = __expf(m_r[r] - mn);
    m_r[r] = mn;
  }
  float ls[4] = {0.f, 0.f, 0.f, 0.f};
#pragma unroll
  for (int nb = 0; nb < 4; ++nb)
#pragma unroll
    for (int r = 0; r < 4; ++r) {
      float pp = __expf(sv[nb][r] - m_r[r]);
      sv[nb][r] = pp;
      ls[r] += pp;
    }
#pragma unroll
  for (int xm = 1; xm < 16; xm <<= 1)
#pragma unroll
    for (int r = 0; r < 4; ++r) ls[r] += __shfl_xor(ls[r], xm, 64);
#pragma unroll
  for (int r = 0; r < 4; ++r) l_r[r] = l_r[r] * al[r] + ls[r];
#pragma unroll
  for (int nb = 0; nb < 8; ++nb)
#pragma unroll
    for (int r = 0; r < 4; ++r) acc_o[nb][r] *= al[r];

#pragma unroll
  for (int nb = 0; nb < 4; ++nb)
#pragma unroll
    for (int r = 0; r < 4; ++r)
      p_w[(g * 4 + r) * 72 + (nb << 4) + c] = f2bf(sv[nb][r]);

#pragma unroll
  for (int ks = 0; ks < 2; ++ks) {
    bf16x8 pa = *(const bf16x8*)((const char*)p_w + c * 144 + ks * 64 + g * 16);
#pragma unroll
    for (int nb = 0; nb < 8; ++nb) {
      int n = (nb << 4) + c;
      int off = (n << 7) + (ks << 6) + (g << 4);
      bf16x8 vf = *(const bf16x8*)((const char*)v_lds + (off ^ ((n & 7) << 4)));
      acc_o[nb] = mfma16(pa, vf, acc_o[nb]);
    }
  }
}

// work map: j<256 -> (b=j>>5, qi=j&31, half0: tiles [0,T/2));
//           j>=256 -> (b, qi=31-(u&31), half1: tiles [T/2,T)). Pairs (j, j+256) balance.
__global__ __launch_bounds__(256) void flash_attn(
    const short* __restrict__ qp, const short* __restrict__ kp, const short* __restrict__ vt,
    const int* __restrict__ pad, float* __restrict__ partO, float* __restrict__ partML) {
  __shared__ short k_lds[2][64 * 128];
  __shared__ short v_lds[2][128 * 64];
  __shared__ short p_lds[4][16 * 72];
  const int tid = threadIdx.x, w = tid >> 6, lane = tid & 63;
  const int g = lane >> 4, c = lane & 15;
  const int j = blockIdx.x;
  int b, qi, half;
  if (j < 256) { b = j >> 5; qi = j & 31; half = 0; }
  else { int u = j - 256; b = u >> 5; qi = 31 - (u & 31); half = 1; }
  const int T = qi + 1;
  const int t0 = half ? (T >> 1) : 0;
  const int t1 = half ? T : (T >> 1);
  const int q0 = qi << 6;

  bf16x8 qf[4];
  {
    int token = (b << 11) + q0 + (w << 4) + c;
    const char* qrow = (const char*)qp + (size_t)token * 256;
#pragma unroll
    for (int s = 0; s < 4; ++s) qf[s] = *(const bf16x8*)(qrow + s * 64 + g * 16);
  }
  f32x4 acc_o[8];
#pragma unroll
  for (int i = 0; i < 8; ++i) acc_o[i] = (f32x4){0.f, 0.f, 0.f, 0.f};
  float m_r[4] = {-1e30f, -1e30f, -1e30f, -1e30f};
  float l_r[4] = {0.f, 0.f, 0.f, 0.f};

  const char* kb_base = (const char*)kp + (size_t)(b << 11) * 256;
  const char* vb_base = (const char*)vt + (size_t)b * 524288;
  const int* padp = pad + (b << 11);
  const int qrow_g = q0 + (w << 4) + (g << 2);

  if (t1 > t0) {
    stage_kv(k_lds[0], v_lds[0], kb_base, vb_base, t0, w, lane);
    __syncthreads();
    int cur = 0;
    for (int t = t0; t < t1; ++t) {
      if (t + 1 < t1)
        stage_kv(k_lds[cur ^ 1], v_lds[cur ^ 1], kb_base, vb_base, t + 1, w, lane);
      if (half && t == T - 1)
        attn_tile<true>(k_lds[cur], v_lds[cur], p_lds[w], qf, acc_o, m_r, l_r,
                        padp, t << 6, qrow_g, g, c);
      else
        attn_tile<false>(k_lds[cur], v_lds[cur], p_lds[w], qf, acc_o, m_r, l_r,
                         padp, t << 6, qrow_g, g, c);
      __syncthreads();
      cur ^= 1;
    }
  }

  float* pO = partO + (size_t)j * (64 * 128);
  float* pML = partML + (size_t)j * 128;
#pragma unroll
  for (int nb = 0; nb < 8; ++nb)
#pragma unroll
    for (int r = 0; r < 4; ++r)
      pO[(w * 16 + g * 4 + r) * 128 + (nb << 4) + c] = acc_o[nb][r];
  if (c == 0)
#pragma unroll
    for (int r = 0; r < 4; ++r) {
      pML[(w * 16 + g * 4 + r) * 2] = m_r[r];
      pML[(w * 16 + g * 4 + r) * 2 + 1] = l_r[r];
    }
}

// ---------------- combine: merge 2 partials, degenerate fixup ----------------
__global__ __launch_bounds__(256) void combine_kernel(
    const float* __restrict__ partO, const float* __restrict__ partML,
    const float* __restrict__ avgv, float* __restrict__ out) {
  int gid = blockIdx.x * 256 + threadIdx.x;   // 524288 float4s
  int row = gid >> 5;
  int d4 = gid & 31;
  int b = row >> 11, s = row & 2047;
  int qt = s >> 6, lr = s & 63;
  int wid1 = (b << 5) + qt;
  int wid2 = 256 + (b << 5) + (31 - qt);
  float m1 = partML[wid1 * 128 + lr * 2], l1 = partML[wid1 * 128 + lr * 2 + 1];
  float m2 = partML[wid2 * 128 + lr * 2], l2 = partML[wid2 * 128 + lr * 2 + 1];
  float m = fmaxf(m1, m2);
  f32x4 o;
  if (m < -1e8f) {
    o = *(const f32x4*)(avgv + (b << 7) + (d4 << 2));
  } else {
    float f1 = __expf(m1 - m), f2 = __expf(m2 - m);
    float inv = 1.0f / (l1 * f1 + l2 * f2);
    f32x4 o1 = *(const f32x4*)(partO + ((size_t)wid1 * 64 + lr) * 128 + (d4 << 2));
    f32x4 o2 = *(const f32x4*)(partO + ((size_t)wid2 * 64 + lr) * 128 + (d4 << 2));
#pragma unroll
    for (int k = 0; k < 4; ++k) o[k] = (o1[k] * f1 + o2[k] * f2) * inv;
  }
  *(f32x4*)(out + (size_t)row * 128 + (d4 << 2)) = o;
}

extern "C" void kernel_launch(void* const* d_in, const int* in_sizes, int n_in,
                              void* d_out, int out_size, void* d_ws, size_t ws_size,
                              hipStream_t stream) {
  const int*   pad   = (const int*)d_in[0];
  const float* query = (const float*)d_in[1];
  const float* key   = (const float*)d_in[2];
  const float* value = (const float*)d_in[3];
  const float* Wq    = (const float*)d_in[4];
  const float* bq    = (const float*)d_in[5];
  const float* Wk    = (const float*)d_in[6];
  const float* bk    = (const float*)d_in[7];
  const float* Wv    = (const float*)d_in[8];
  const float* bv    = (const float*)d_in[9];
  char* ws = (char*)d_ws;
  short* wt    = (short*)ws;                      // 768KB (fragment-ordered)
  short* qp    = (short*)(ws + 786432);           // 4MB
  short* kp    = (short*)(ws + 4980736);          // 4MB
  short* vt    = (short*)(ws + 9175040);          // 4MB  vT[8][128][2048]
  float* partO = (float*)(ws + 13369344);         // 512*64*128*4 = 16MB
  float* partML= (float*)(ws + 30146560);         // 512*64*2*4 = 256KB
  float* avgv  = (float*)(ws + 30408704);         // 4KB
  float* out   = (float*)d_out;

  prep_weights<<<dim3(192), dim3(256), 0, stream>>>(Wq, Wk, Wv, wt);
  proj_gemm<<<dim3(768), dim3(256), 0, stream>>>(query, key, value, wt, bq, bk, bv, qp, kp, vt);
  avgv2_kernel<<<dim3(64), dim3(256), 0, stream>>>(vt, pad, bv, avgv);
  flash_attn<<<dim3(512), dim3(256), 0, stream>>>(qp, kp, vt, pad, partO, partML);
  combine_kernel<<<dim3(2048), dim3(256), 0, stream>>>(partO, partML, avgv, out);
}